// Round 5
// baseline (53.351 us; speedup 1.0000x reference)
//
#include <hip/hip_runtime.h>
#include <hip/hip_bf16.h>
#include <cstdint>

#define NPIX (16 * 256 * 256)
#define THRV 0.1f

typedef __bf16 bf16x8 __attribute__((ext_vector_type(8)));
typedef float  f32x4  __attribute__((ext_vector_type(4)));

// wpack slots (slot*64 + lane, float4 each):
//  0..3 w1f[n]   4..11 w2f[s*4+n]   12..13 w3f[s]   14..17 b2v[n]
#define NSLOT 18

// ---------------------------------------------------------------------------
// k_pack: one wave builds per-lane weight fragments.
// psi(s,g,j) = (2s+(j>>2))*16 + g*4 + (j&3): layer N's C regs ARE layer N+1's
// B-frag (zero-shuffle MLP). w1 rows 16..31/32..47 pre-summed (broadcast sx/sy),
// b1 rides k-slot (g==1,j==4) with activation 1.0.
// ---------------------------------------------------------------------------
__global__ __launch_bounds__(64) void k_pack(const float* __restrict__ w1,
                                             const float* __restrict__ b1,
                                             const float* __restrict__ w2,
                                             const float* __restrict__ b2,
                                             const float* __restrict__ w3,
                                             float4* __restrict__ wpack) {
    const int lane = threadIdx.x;
    const int r = lane & 15, g = lane >> 4;
#pragma unroll
    for (int n = 0; n < 4; ++n) {
        const int cc = n * 16 + r;
        bf16x8 f;
#pragma unroll
        for (int j = 0; j < 8; ++j) {
            float v = 0.f;
            if (j < 4) v = w1[(g * 4 + j) * 64 + cc];
            else if (g == 0 && j == 4) { for (int t = 0; t < 16; ++t) v += w1[(16 + t) * 64 + cc]; }
            else if (g == 0 && j == 5) { for (int t = 0; t < 16; ++t) v += w1[(32 + t) * 64 + cc]; }
            else if (g == 1 && j == 4) v = b1[cc];
            f[j] = (__bf16)v;
        }
        wpack[n * 64 + lane] = *(const float4*)&f;
    }
#pragma unroll
    for (int s = 0; s < 2; ++s)
#pragma unroll
        for (int n = 0; n < 4; ++n) {
            bf16x8 f;
#pragma unroll
            for (int j = 0; j < 8; ++j) {
                const int psi = (2 * s + (j >> 2)) * 16 + g * 4 + (j & 3);
                f[j] = (__bf16)w2[psi * 64 + n * 16 + r];
            }
            wpack[(4 + s * 4 + n) * 64 + lane] = *(const float4*)&f;
        }
#pragma unroll
    for (int s = 0; s < 2; ++s) {
        bf16x8 f;
#pragma unroll
        for (int j = 0; j < 8; ++j) {
            const int psi = (2 * s + (j >> 2)) * 16 + g * 4 + (j & 3);
            f[j] = (__bf16)w3[psi * 16 + r];
        }
        wpack[(12 + s) * 64 + lane] = *(const float4*)&f;
    }
#pragma unroll
    for (int n = 0; n < 4; ++n) {
        f32x4 v;
#pragma unroll
        for (int q = 0; q < 4; ++q) v[q] = b2[n * 16 + g * 4 + q];
        wpack[(14 + n) * 64 + lane] = *(const float4*)&v;
    }
}

// ---------------------------------------------------------------------------
// k_fused: block = 4-row band of one image (1024 px), 512 threads (8 waves).
// Phase 1a: wave w owns half-row (row w>>1, cols (w&1)*128..+127) = 8 tiles;
//   lane (g,r) loads pixel r's channels 4g..4g+3 (float4, kept in regs for the
//   MLP) -> channel-sum via 2 shfl_xor -> s into LDS; ch3 plane from g==0.
// Phase 1b: halo rows y0-1, y0+4: 1 px/thread, 4 float4 -> s (0 outside).
// Phase 2a: gx/gy (full 3x3 sobel from s) + pre-life row-flag per pixel.
// Phase 2:  deep-prefetched in-register MFMA MLP (x already resident),
//   gx/gy via LDS broadcast, NT store of x_new, post-life byte flag.
// ---------------------------------------------------------------------------
__global__ __launch_bounds__(512, 2) void k_fused(const float* __restrict__ x,
                                                  const float4* __restrict__ wpack,
                                                  float* __restrict__ out,
                                                  unsigned char* __restrict__ rpre,
                                                  unsigned char* __restrict__ anewf) {
    __shared__ float sS[6][256];    // s rows y0-1 .. y0+4
    __shared__ float sC3[4][256];   // ch3, interior rows
    __shared__ float sGx[4][256];
    __shared__ float sGy[4][256];

    const int tid = threadIdx.x;
    const int wv = tid >> 6, lane = tid & 63;
    const int r = lane & 15, g = lane >> 4;

    // ---- weight fragments ----
    bf16x8 w1f[4], w2f[2][4], w3f[2];
    f32x4 b2v[4];
#pragma unroll
    for (int n = 0; n < 4; ++n) { float4 t = wpack[n * 64 + lane]; w1f[n] = *(bf16x8*)&t; }
#pragma unroll
    for (int s2 = 0; s2 < 2; ++s2)
#pragma unroll
        for (int n = 0; n < 4; ++n) { float4 t = wpack[(4 + s2 * 4 + n) * 64 + lane]; w2f[s2][n] = *(bf16x8*)&t; }
#pragma unroll
    for (int s2 = 0; s2 < 2; ++s2) { float4 t = wpack[(12 + s2) * 64 + lane]; w3f[s2] = *(bf16x8*)&t; }
#pragma unroll
    for (int n = 0; n < 4; ++n) { float4 t = wpack[(14 + n) * 64 + lane]; b2v[n] = *(f32x4*)&t; }

    const int band = blockIdx.x;               // 64 bands/image * 16 images
    const int bi = band >> 6;
    const int y0 = (band & 63) * 4;
    const size_t ibase = ((size_t)bi) << 16;   // pixel base of image
    const int wrow = wv >> 1;                  // 0..3 (row in band)
    const int wcol = (wv & 1) * 128;

    // ---- phase 1a: interior x loads (deep prefetch) + s ----
    float4 xf[8];
#pragma unroll
    for (int t = 0; t < 8; ++t) {
        const int col = wcol + t * 16 + r;
        const size_t pix = ibase + (size_t)(y0 + wrow) * 256 + col;
        xf[t] = *(const float4*)(x + pix * 16 + g * 4);
        float p = ((xf[t].x + xf[t].y) + (xf[t].z + xf[t].w));
        p += __shfl_xor(p, 16);
        p += __shfl_xor(p, 32);
        if (g == 0) {
            sS[wrow + 1][col] = p;
            sC3[wrow][col] = xf[t].w;
        }
    }

    // ---- phase 1b: halo s rows ----
    {
        const int hrow = (tid < 256) ? (y0 - 1) : (y0 + 4);
        const int hcol = tid & 255;
        float sv = 0.f;
        if ((unsigned)hrow < 256u) {
            const float4* hp = (const float4*)(x + (ibase + (size_t)hrow * 256 + hcol) * 16);
            float4 q0 = hp[0], q1 = hp[1], q2 = hp[2], q3 = hp[3];
            sv = ((q0.x + q0.y) + (q0.z + q0.w)) + ((q1.x + q1.y) + (q1.z + q1.w)) +
                 ((q2.x + q2.y) + (q2.z + q2.w)) + ((q3.x + q3.y) + (q3.z + q3.w));
        }
        sS[(tid < 256) ? 0 : 5][hcol] = sv;
    }
    __syncthreads();

    // ---- phase 2a: sobel + pre-life flag (2 px/thread) ----
#pragma unroll
    for (int k = 0; k < 2; ++k) {
        const int idx = tid + k * 512;     // 0..1023
        const int row = idx >> 8;          // 0..3
        const int c = idx & 255;
        const bool cl = (c > 0), cr = (c < 255);
        const float r0m = cl ? sS[row][c - 1] : 0.f;
        const float r0c = sS[row][c];
        const float r0p = cr ? sS[row][c + 1] : 0.f;
        const float r1m = cl ? sS[row + 1][c - 1] : 0.f;
        const float r1p = cr ? sS[row + 1][c + 1] : 0.f;
        const float r2m = cl ? sS[row + 2][c - 1] : 0.f;
        const float r2c = sS[row + 2][c];
        const float r2p = cr ? sS[row + 2][c + 1] : 0.f;
        sGx[row][c] = ((r0p - r0m) + 2.f * (r1p - r1m) + (r2p - r2m)) * 0.125f;
        sGy[row][c] = ((r2m + 2.f * r2c + r2p) - (r0m + 2.f * r0c + r0p)) * 0.125f;
        // pre-life horizontal 3-max (0-pad safe: THR > 0)
        const float c3m = cl ? sC3[row][c - 1] : 0.f;
        const float c3c = sC3[row][c];
        const float c3p = cr ? sC3[row][c + 1] : 0.f;
        const float m3 = fmaxf(c3m, fmaxf(c3c, c3p));
        rpre[ibase + (size_t)(y0 + row) * 256 + c] = (m3 > THRV) ? 1 : 0;
    }
    __syncthreads();

    // ---- phase 2: MFMA MLP, fully unrolled over 8 tiles ----
#pragma unroll
    for (int t = 0; t < 8; ++t) {
        const int col = wcol + t * 16 + r;
        const size_t pix = ibase + (size_t)(y0 + wrow) * 256 + col;
        const float gx = sGx[wrow][col];   // broadcast within 16-lane groups
        const float gy = sGy[wrow][col];

        bf16x8 a1;
        a1[0] = (__bf16)xf[t].x; a1[1] = (__bf16)xf[t].y;
        a1[2] = (__bf16)xf[t].z; a1[3] = (__bf16)xf[t].w;
        a1[4] = (__bf16)(g == 0 ? gx : (g == 1 ? 1.f : 0.f));
        a1[5] = (__bf16)(g == 0 ? gy : 0.f);
        a1[6] = (__bf16)0.f; a1[7] = (__bf16)0.f;

        f32x4 acc1[4];
#pragma unroll
        for (int n = 0; n < 4; ++n)
            acc1[n] = __builtin_amdgcn_mfma_f32_16x16x32_bf16(
                w1f[n], a1, (f32x4){0.f, 0.f, 0.f, 0.f}, 0, 0, 0);

        bf16x8 bf2[2];
#pragma unroll
        for (int s2 = 0; s2 < 2; ++s2)
#pragma unroll
            for (int j = 0; j < 4; ++j) {
                bf2[s2][j]     = (__bf16)fmaxf(acc1[2 * s2][j], 0.f);
                bf2[s2][4 + j] = (__bf16)fmaxf(acc1[2 * s2 + 1][j], 0.f);
            }

        f32x4 acc2[4];
#pragma unroll
        for (int n = 0; n < 4; ++n) {
            acc2[n] = b2v[n];
            acc2[n] = __builtin_amdgcn_mfma_f32_16x16x32_bf16(w2f[0][n], bf2[0], acc2[n], 0, 0, 0);
            acc2[n] = __builtin_amdgcn_mfma_f32_16x16x32_bf16(w2f[1][n], bf2[1], acc2[n], 0, 0, 0);
        }

        bf16x8 bf3[2];
#pragma unroll
        for (int s2 = 0; s2 < 2; ++s2)
#pragma unroll
            for (int j = 0; j < 4; ++j) {
                bf3[s2][j]     = (__bf16)fmaxf(acc2[2 * s2][j], 0.f);
                bf3[s2][4 + j] = (__bf16)fmaxf(acc2[2 * s2 + 1][j], 0.f);
            }

        f32x4 acc3 = __builtin_amdgcn_mfma_f32_16x16x32_bf16(
            w3f[0], bf3[0], (f32x4){0.f, 0.f, 0.f, 0.f}, 0, 0, 0);
        acc3 = __builtin_amdgcn_mfma_f32_16x16x32_bf16(w3f[1], bf3[1], acc3, 0, 0, 0);

        f32x4 xn;
        xn[0] = xf[t].x + acc3[0]; xn[1] = xf[t].y + acc3[1];
        xn[2] = xf[t].z + acc3[2]; xn[3] = xf[t].w + acc3[3];
        __builtin_nontemporal_store(xn, (f32x4*)(out + pix * 16 + g * 4));
        if (g == 0) anewf[pix] = (xn[3] > THRV) ? 1 : 0;
    }
}

// ---------------------------------------------------------------------------
// k_post: thread = 4 pixels; bit-parallel life from byte flags.
// pre = vertical OR of rpre (already row-maxed); post = 3x3 OR of anewf.
// ---------------------------------------------------------------------------
__global__ __launch_bounds__(256) void k_post(const unsigned char* __restrict__ rpre,
                                              const unsigned char* __restrict__ anewf,
                                              float* __restrict__ out) {
    const int q = blockIdx.x * 256 + threadIdx.x;
    const int p0 = q * 4;
    const int bi = p0 >> 16;
    const int rem = p0 & 65535;
    const int y = rem >> 8;
    const int c0 = rem & 255;
    const unsigned char* pr = rpre + ((size_t)bi << 16);
    const unsigned char* an = anewf + ((size_t)bi << 16);

    unsigned pre = 0, M = 0, l = 0, rr = 0;
#pragma unroll
    for (int dy = -1; dy <= 1; ++dy) {
        const int y2 = y + dy;
        if ((unsigned)y2 >= 256u) continue;
        const int ro = y2 * 256;
        pre |= *(const unsigned*)(pr + ro + c0);
        M   |= *(const unsigned*)(an + ro + c0);
        l   |= (c0 > 0)   ? (unsigned)an[ro + c0 - 1] : 0u;
        rr  |= (c0 < 252) ? (unsigned)an[ro + c0 + 4] : 0u;
    }
    const unsigned post = M | (M << 8) | l | (M >> 8) | (rr << 24);
    const unsigned alive = pre & post;
    if (alive != 0x01010101u) {
        const f32x4 z = (f32x4){0.f, 0.f, 0.f, 0.f};
#pragma unroll
        for (int i = 0; i < 4; ++i)
            if (!((alive >> (8 * i)) & 1u)) {
                f32x4* op = (f32x4*)(out + (size_t)(p0 + i) * 16);
                op[0] = z; op[1] = z; op[2] = z; op[3] = z;
            }
    }
}

// ---------------------------------------------------------------------------
extern "C" void kernel_launch(void* const* d_in, const int* in_sizes, int n_in,
                              void* d_out, int out_size, void* d_ws, size_t ws_size,
                              hipStream_t stream) {
    const float* x  = (const float*)d_in[0];
    const float* w1 = (const float*)d_in[1];
    const float* b1 = (const float*)d_in[2];
    const float* w2 = (const float*)d_in[3];
    const float* b2 = (const float*)d_in[4];
    const float* w3 = (const float*)d_in[5];
    float* out = (float*)d_out;

    unsigned char* rpre  = (unsigned char*)d_ws;       // NPIX bytes
    unsigned char* anewf = rpre + NPIX;                // NPIX bytes
    float4* wpack = (float4*)(anewf + NPIX);           // NSLOT*64 float4

    hipLaunchKernelGGL(k_pack, dim3(1), dim3(64), 0, stream, w1, b1, w2, b2, w3, wpack);
    hipLaunchKernelGGL(k_fused, dim3(NPIX / 1024), dim3(512), 0, stream,
                       x, wpack, out, rpre, anewf);
    hipLaunchKernelGGL(k_post, dim3(NPIX / 1024), dim3(256), 0, stream,
                       rpre, anewf, out);
}

// Round 6
// 49.040 us; speedup vs baseline: 1.0879x; 1.0879x over previous
//
#include <hip/hip_runtime.h>
#include <hip/hip_bf16.h>
#include <cstdint>

#define NPIX (16 * 256 * 256)
#define THRV 0.1f

typedef __bf16 bf16x8 __attribute__((ext_vector_type(8)));
typedef float  f32x4  __attribute__((ext_vector_type(4)));

// wpack slots (slot*64 + lane, float4 each):
//  0..3 w1f[n]   4..11 w2f[s*4+n]   12..13 w3f[s]   14..17 b2v[n]
#define NSLOT 18

// ---------------------------------------------------------------------------
// k_prep: block = one image row. s = channel sum; writes interleaved sobel
// halves hxs = (hx, hs) with hx = s(x+1)-s(x-1), hs = s(x-1)+2s(x)+s(x+1)
// (zero column padding via LDS), plus pre-life row-max byte flag.
// Block 0, lanes<64: one-time weight fragment pack.
// psi(s,g,j) = (2s+(j>>2))*16 + g*4 + (j&3): layer N's C regs ARE layer N+1's
// B-frag -> zero-shuffle in-register MLP.
// ---------------------------------------------------------------------------
__global__ __launch_bounds__(256) void k_prep(const float* __restrict__ x,
                                              const float* __restrict__ w1,
                                              const float* __restrict__ b1,
                                              const float* __restrict__ w2,
                                              const float* __restrict__ b2,
                                              const float* __restrict__ w3,
                                              float2* __restrict__ hxs,
                                              unsigned char* __restrict__ rpre,
                                              float4* __restrict__ wpack) {
    __shared__ float sS[258];
    __shared__ float sA[258];
    const int tid = threadIdx.x;
    const int p = blockIdx.x * 256 + tid;

    const float4* xp = (const float4*)(x + (size_t)p * 16);
    float4 a = xp[0], b = xp[1], c = xp[2], d = xp[3];
    float sum = ((a.x + a.y) + (a.z + a.w)) + ((b.x + b.y) + (b.z + b.w)) +
                ((c.x + c.y) + (c.z + c.w)) + ((d.x + d.y) + (d.z + d.w));
    sS[tid + 1] = sum;
    sA[tid + 1] = a.w;  // channel 3
    if (tid == 0) { sS[0] = 0.f; sS[257] = 0.f; sA[0] = -1e30f; sA[257] = -1e30f; }
    __syncthreads();

    hxs[p] = make_float2(sS[tid + 2] - sS[tid],
                         sS[tid] + 2.f * sS[tid + 1] + sS[tid + 2]);
    float rm = fmaxf(sA[tid], fmaxf(sA[tid + 1], sA[tid + 2]));
    rpre[p] = (rm > THRV) ? 1 : 0;

    if (blockIdx.x == 0 && tid < 64) {
        const int lane = tid;
        const int r = lane & 15, g = lane >> 4;
#pragma unroll
        for (int n = 0; n < 4; ++n) {
            const int cc = n * 16 + r;
            bf16x8 f;
#pragma unroll
            for (int j = 0; j < 8; ++j) {
                float v = 0.f;
                if (j < 4) v = w1[(g * 4 + j) * 64 + cc];
                else if (g == 0 && j == 4) { for (int t = 0; t < 16; ++t) v += w1[(16 + t) * 64 + cc]; }
                else if (g == 0 && j == 5) { for (int t = 0; t < 16; ++t) v += w1[(32 + t) * 64 + cc]; }
                else if (g == 1 && j == 4) v = b1[cc];
                f[j] = (__bf16)v;
            }
            wpack[n * 64 + lane] = *(const float4*)&f;
        }
#pragma unroll
        for (int s = 0; s < 2; ++s)
#pragma unroll
            for (int n = 0; n < 4; ++n) {
                bf16x8 f;
#pragma unroll
                for (int j = 0; j < 8; ++j) {
                    const int psi = (2 * s + (j >> 2)) * 16 + g * 4 + (j & 3);
                    f[j] = (__bf16)w2[psi * 64 + n * 16 + r];
                }
                wpack[(4 + s * 4 + n) * 64 + lane] = *(const float4*)&f;
            }
#pragma unroll
        for (int s = 0; s < 2; ++s) {
            bf16x8 f;
#pragma unroll
            for (int j = 0; j < 8; ++j) {
                const int psi = (2 * s + (j >> 2)) * 16 + g * 4 + (j & 3);
                f[j] = (__bf16)w3[psi * 16 + r];
            }
            wpack[(12 + s) * 64 + lane] = *(const float4*)&f;
        }
#pragma unroll
        for (int n = 0; n < 4; ++n) {
            f32x4 v;
#pragma unroll
            for (int q = 0; q < 4; ++q) v[q] = b2[n * 16 + g * 4 + q];
            wpack[(14 + n) * 64 + lane] = *(const float4*)&v;
        }
    }
}

// ---------------------------------------------------------------------------
// k_mfma: block = one image row (4 waves x 64 px), no LDS, no barriers.
// All 4 tiles' loads issued up front; 4 independent MFMA chains per wave.
// Sobel: lane g<3 loads (hx,hs) of row y+g-1; combine via 2 shfl_xor:
//   gx = (hx(y-1)+2hx(y)+hx(y+1))/8, gy = (hs(y+1)-hs(y-1))/8.
// XCD swizzle: rows grouped 512-per-XCD so hxs row reuse is L2-local.
// ---------------------------------------------------------------------------
__global__ __launch_bounds__(256) void k_mfma(const float* __restrict__ x,
                                              const float2* __restrict__ hxs,
                                              const float4* __restrict__ wpack,
                                              float* __restrict__ out,
                                              unsigned char* __restrict__ anewf) {
    const int tid = threadIdx.x;
    const int wv = tid >> 6, lane = tid & 63;
    const int r = lane & 15, g = lane >> 4;

    bf16x8 w1f[4], w2f[2][4], w3f[2];
    f32x4 b2v[4];
#pragma unroll
    for (int n = 0; n < 4; ++n) { float4 t = wpack[n * 64 + lane]; w1f[n] = *(bf16x8*)&t; }
#pragma unroll
    for (int s2 = 0; s2 < 2; ++s2)
#pragma unroll
        for (int n = 0; n < 4; ++n) { float4 t = wpack[(4 + s2 * 4 + n) * 64 + lane]; w2f[s2][n] = *(bf16x8*)&t; }
#pragma unroll
    for (int s2 = 0; s2 < 2; ++s2) { float4 t = wpack[(12 + s2) * 64 + lane]; w3f[s2] = *(bf16x8*)&t; }
#pragma unroll
    for (int n = 0; n < 4; ++n) { float4 t = wpack[(14 + n) * 64 + lane]; b2v[n] = *(f32x4*)&t; }

    const int row = (blockIdx.x & 7) * 512 + (blockIdx.x >> 3);  // bijective
    const int y = row & 255;
    const size_t rbase = (size_t)row * 256;   // pixel index of row start
    const int wcol = wv * 64;

    const int y2 = y + g - 1;
    const bool gok = (g < 3) & ((unsigned)y2 < 256u);
    const size_t hbase = ((rbase >> 8) << 8) * 1 + ((size_t)(row >> 8) << 16); // image base
    // hxs row pointer (deref only when gok)
    const float2* hrow = hxs + ((size_t)(row >> 8) << 16) + (size_t)(gok ? y2 : 0) * 256;

    // ---- issue all loads ----
    float4 xf[4]; float2 hv[4];
#pragma unroll
    for (int t = 0; t < 4; ++t) {
        const int col = wcol + t * 16 + r;
        xf[t] = *(const float4*)(x + (rbase + col) * 16 + g * 4);
        hv[t] = gok ? hrow[col] : make_float2(0.f, 0.f);
    }

    // ---- 4 independent tile chains ----
#pragma unroll
    for (int t = 0; t < 4; ++t) {
        const int col = wcol + t * 16 + r;
        const size_t pix = rbase + col;

        float ax = hv[t].x * ((g == 1) ? 2.f : 1.f);
        float ay = (g == 2) ? hv[t].y : ((g == 0) ? -hv[t].y : 0.f);
        ax += __shfl_xor(ax, 16); ax += __shfl_xor(ax, 32);
        ay += __shfl_xor(ay, 16); ay += __shfl_xor(ay, 32);
        const float gx = ax * 0.125f;
        const float gy = ay * 0.125f;

        bf16x8 a1;
        a1[0] = (__bf16)xf[t].x; a1[1] = (__bf16)xf[t].y;
        a1[2] = (__bf16)xf[t].z; a1[3] = (__bf16)xf[t].w;
        a1[4] = (__bf16)(g == 0 ? gx : (g == 1 ? 1.f : 0.f));
        a1[5] = (__bf16)(g == 0 ? gy : 0.f);
        a1[6] = (__bf16)0.f; a1[7] = (__bf16)0.f;

        f32x4 acc1[4];
#pragma unroll
        for (int n = 0; n < 4; ++n)
            acc1[n] = __builtin_amdgcn_mfma_f32_16x16x32_bf16(
                w1f[n], a1, (f32x4){0.f, 0.f, 0.f, 0.f}, 0, 0, 0);

        bf16x8 bf2[2];
#pragma unroll
        for (int s2 = 0; s2 < 2; ++s2)
#pragma unroll
            for (int j = 0; j < 4; ++j) {
                bf2[s2][j]     = (__bf16)fmaxf(acc1[2 * s2][j], 0.f);
                bf2[s2][4 + j] = (__bf16)fmaxf(acc1[2 * s2 + 1][j], 0.f);
            }

        f32x4 acc2[4];
#pragma unroll
        for (int n = 0; n < 4; ++n) {
            acc2[n] = b2v[n];
            acc2[n] = __builtin_amdgcn_mfma_f32_16x16x32_bf16(w2f[0][n], bf2[0], acc2[n], 0, 0, 0);
            acc2[n] = __builtin_amdgcn_mfma_f32_16x16x32_bf16(w2f[1][n], bf2[1], acc2[n], 0, 0, 0);
        }

        bf16x8 bf3[2];
#pragma unroll
        for (int s2 = 0; s2 < 2; ++s2)
#pragma unroll
            for (int j = 0; j < 4; ++j) {
                bf3[s2][j]     = (__bf16)fmaxf(acc2[2 * s2][j], 0.f);
                bf3[s2][4 + j] = (__bf16)fmaxf(acc2[2 * s2 + 1][j], 0.f);
            }

        f32x4 acc3 = __builtin_amdgcn_mfma_f32_16x16x32_bf16(
            w3f[0], bf3[0], (f32x4){0.f, 0.f, 0.f, 0.f}, 0, 0, 0);
        acc3 = __builtin_amdgcn_mfma_f32_16x16x32_bf16(w3f[1], bf3[1], acc3, 0, 0, 0);

        f32x4 xn;
        xn[0] = xf[t].x + acc3[0]; xn[1] = xf[t].y + acc3[1];
        xn[2] = xf[t].z + acc3[2]; xn[3] = xf[t].w + acc3[3];
        __builtin_nontemporal_store(xn, (f32x4*)(out + pix * 16 + g * 4));
        if (g == 0) anewf[pix] = (xn[3] > THRV) ? 1 : 0;
    }
}

// ---------------------------------------------------------------------------
// k_post: thread = 4 pixels; bit-parallel life from byte flags.
// pre = vertical OR of rpre (already row-maxed); post = 3x3 OR of anewf.
// ---------------------------------------------------------------------------
__global__ __launch_bounds__(256) void k_post(const unsigned char* __restrict__ rpre,
                                              const unsigned char* __restrict__ anewf,
                                              float* __restrict__ out) {
    const int q = blockIdx.x * 256 + threadIdx.x;
    const int p0 = q * 4;
    const int bi = p0 >> 16;
    const int rem = p0 & 65535;
    const int y = rem >> 8;
    const int c0 = rem & 255;
    const unsigned char* pr = rpre + ((size_t)bi << 16);
    const unsigned char* an = anewf + ((size_t)bi << 16);

    unsigned pre = 0, M = 0, l = 0, rr = 0;
#pragma unroll
    for (int dy = -1; dy <= 1; ++dy) {
        const int y2 = y + dy;
        if ((unsigned)y2 >= 256u) continue;
        const int ro = y2 * 256;
        pre |= *(const unsigned*)(pr + ro + c0);
        M   |= *(const unsigned*)(an + ro + c0);
        l   |= (c0 > 0)   ? (unsigned)an[ro + c0 - 1] : 0u;
        rr  |= (c0 < 252) ? (unsigned)an[ro + c0 + 4] : 0u;
    }
    const unsigned post = M | (M << 8) | l | (M >> 8) | (rr << 24);
    const unsigned alive = pre & post;
    if (alive != 0x01010101u) {
        const f32x4 z = (f32x4){0.f, 0.f, 0.f, 0.f};
#pragma unroll
        for (int i = 0; i < 4; ++i)
            if (!((alive >> (8 * i)) & 1u)) {
                f32x4* op = (f32x4*)(out + (size_t)(p0 + i) * 16);
                op[0] = z; op[1] = z; op[2] = z; op[3] = z;
            }
    }
}

// ---------------------------------------------------------------------------
extern "C" void kernel_launch(void* const* d_in, const int* in_sizes, int n_in,
                              void* d_out, int out_size, void* d_ws, size_t ws_size,
                              hipStream_t stream) {
    const float* x  = (const float*)d_in[0];
    const float* w1 = (const float*)d_in[1];
    const float* b1 = (const float*)d_in[2];
    const float* w2 = (const float*)d_in[3];
    const float* b2 = (const float*)d_in[4];
    const float* w3 = (const float*)d_in[5];
    float* out = (float*)d_out;

    float2* hxs = (float2*)d_ws;                        // NPIX float2 (8 MB)
    unsigned char* rpre  = (unsigned char*)(hxs + NPIX); // NPIX bytes
    unsigned char* anewf = rpre + NPIX;                  // NPIX bytes
    float4* wpack = (float4*)(anewf + NPIX);             // NSLOT*64 float4

    hipLaunchKernelGGL(k_prep, dim3(NPIX / 256), dim3(256), 0, stream,
                       x, w1, b1, w2, b2, w3, hxs, rpre, wpack);
    hipLaunchKernelGGL(k_mfma, dim3(NPIX / 256), dim3(256), 0, stream,
                       x, hxs, wpack, out, anewf);
    hipLaunchKernelGGL(k_post, dim3(NPIX / 1024), dim3(256), 0, stream,
                       rpre, anewf, out);
}